// Round 3
// baseline (316.996 us; speedup 1.0000x reference)
//
#include <hip/hip_runtime.h>
#include <hip/hip_cooperative_groups.h>
#include <math.h>
#include <stdint.h>

namespace cg = cooperative_groups;

#define N_BINS 50
#define EDGE_N 51
#define HIST_N 52
#define NBLK 1024
#define NTHR 256

// ws layout:
// float bmin[1024]; float bmax[1024];           (per-block minima/maxima)
// int histU[2*52]; int histE[2*51];             (global hists, zeroed by block 0 phase A)
// @16384: float xcomp[n]                        (compacted column 0)

__device__ __forceinline__ int atom_ldi(const int* p) {
  return __hip_atomic_load(p, __ATOMIC_RELAXED, __HIP_MEMORY_SCOPE_AGENT);
}
__device__ __forceinline__ float atom_ldf(const float* p) {
  return __hip_atomic_load(p, __ATOMIC_RELAXED, __HIP_MEMORY_SCOPE_AGENT);
}
__device__ __forceinline__ void atom_stf(float* p, float v) {
  __hip_atomic_store(p, v, __ATOMIC_RELAXED, __HIP_MEMORY_SCOPE_AGENT);
}
__device__ __forceinline__ void atom_sti(int* p, int v) {
  __hip_atomic_store(p, v, __ATOMIC_RELAXED, __HIP_MEMORY_SCOPE_AGENT);
}

// jnp.linspace(xmin, xmax, 51) float32 semantics:
//   step = e/50 (f32 div); out = xmin*(1-step) + xmax*step; endpoint = xmax exactly.
__device__ __forceinline__ float edge_at(int e, float xmin, float xmax) {
  if (e >= N_BINS) return xmax;
  float step = __fdiv_rn((float)e, (float)N_BINS);
  float omst = __fsub_rn(1.0f, step);
  return __fadd_rn(__fmul_rn(xmin, omst), __fmul_rn(xmax, step));
}

// bce(c) = ((n_f - c)*b + c*a)/n_f in exact f32 op order (no fma contraction)
__device__ __forceinline__ float bce_f(int c, float n_f, float aC, float bC) {
  float cf = (float)c;  // exact, c < 2^24
  float t = __fadd_rn(__fmul_rn(__fsub_rn(n_f, cf), bC), __fmul_rn(cf, aC));
  return __fdiv_rn(t, n_f);
}

__device__ __forceinline__ void get_ab(float& aC, float& bC) {
  const double epsd = (double)1e-7f;
  aC = (float)(-log1p(-epsd));
  bC = (float)(-log(epsd));
}

template <int COMPACT>
__global__ void __launch_bounds__(NTHR, 4)
k_fused(const float4* __restrict__ in4, const int* __restrict__ tgt, int n,
        float* __restrict__ xc, float* __restrict__ bmin, float* __restrict__ bmax,
        int* __restrict__ histU, int* __restrict__ histE, int* __restrict__ out) {
  cg::grid_group grid = cg::this_grid();
  const int tid = threadIdx.x;
  const int bid = blockIdx.x;
  const int gid = bid * NTHR + tid;
  const int stride = NBLK * NTHR;
  const int nv = n >> 2;
  const int base = nv << 2;
  float4* __restrict__ xc4 = (float4*)xc;

  __shared__ float s_wred[2 * (NTHR / 64)];
  __shared__ float s_gminmax[2];
  __shared__ float s_edges[EDGE_N];
  __shared__ int shU[2 * HIST_N];
  __shared__ int shE[2 * EDGE_N];
  __shared__ int s_ns_le[EDGE_N], s_ns_lt[EDGE_N], s_nb_le[EDGE_N], s_nb_lt[EDGE_N];
  __shared__ unsigned char s_mask[EDGE_N];
  __shared__ float s_rv[NTHR];
  __shared__ int s_ri[NTHR];
  __shared__ float s_cut[2];
  __shared__ int s_case;

  // ---------------- Phase A: minmax + compact ----------------
  float vmin = INFINITY, vmax = -INFINITY;
  for (int iv = gid; iv < nv; iv += stride) {
    float4 a = in4[4 * iv + 0];
    float4 b = in4[4 * iv + 1];
    float4 c = in4[4 * iv + 2];
    float4 d = in4[4 * iv + 3];
    vmin = fminf(fminf(vmin, fminf(a.x, b.x)), fminf(c.x, d.x));
    vmax = fmaxf(fmaxf(vmax, fmaxf(a.x, b.x)), fmaxf(c.x, d.x));
    if (COMPACT) xc4[iv] = make_float4(a.x, b.x, c.x, d.x);
  }
  if (bid == 0 && tid < (n - base)) {
    float x = in4[base + tid].x;
    vmin = fminf(vmin, x);
    vmax = fmaxf(vmax, x);
    if (COMPACT) xc[base + tid] = x;
  }
  // block 0 zeroes the global hists while others stream (visible after grid.sync)
  if (bid == 1 % NBLK) {
    for (int i = tid; i < 2 * HIST_N; i += NTHR) atom_sti(&histU[i], 0);
    for (int i = tid; i < 2 * EDGE_N; i += NTHR) atom_sti(&histE[i], 0);
  }
  for (int off = 32; off; off >>= 1) {
    vmin = fminf(vmin, __shfl_down(vmin, off));
    vmax = fmaxf(vmax, __shfl_down(vmax, off));
  }
  {
    int wid = tid >> 6;
    if ((tid & 63) == 0) { s_wred[wid] = vmin; s_wred[(NTHR / 64) + wid] = vmax; }
  }
  __syncthreads();
  if (tid == 0) {
    float m = s_wred[0], M = s_wred[NTHR / 64];
    for (int w = 1; w < NTHR / 64; ++w) {
      m = fminf(m, s_wred[w]);
      M = fmaxf(M, s_wred[(NTHR / 64) + w]);
    }
    atom_stf(&bmin[bid], m);
    atom_stf(&bmax[bid], M);
  }
  grid.sync();

  // ---------------- Phase B: global min/max + histogram ----------------
  {
    float m = INFINITY, M = -INFINITY;
    for (int i = tid; i < NBLK; i += NTHR) {
      m = fminf(m, atom_ldf(&bmin[i]));
      M = fmaxf(M, atom_ldf(&bmax[i]));
    }
    for (int off = 32; off; off >>= 1) {
      m = fminf(m, __shfl_down(m, off));
      M = fmaxf(M, __shfl_down(M, off));
    }
    int wid = tid >> 6;
    if ((tid & 63) == 0) { s_wred[wid] = m; s_wred[(NTHR / 64) + wid] = M; }
    __syncthreads();
    if (tid == 0) {
      float mm = s_wred[0], MM = s_wred[NTHR / 64];
      for (int w = 1; w < NTHR / 64; ++w) {
        mm = fminf(mm, s_wred[w]);
        MM = fmaxf(MM, s_wred[(NTHR / 64) + w]);
      }
      s_gminmax[0] = mm;
      s_gminmax[1] = MM;
    }
    __syncthreads();
  }
  const float xmin = s_gminmax[0];
  const float xmax = s_gminmax[1];
  for (int i = tid; i < 2 * HIST_N; i += NTHR) shU[i] = 0;
  for (int i = tid; i < 2 * EDGE_N; i += NTHR) shE[i] = 0;
  if (tid < EDGE_N) s_edges[tid] = edge_at(tid, xmin, xmax);
  __syncthreads();
  {
    const float delta = __fdiv_rn(__fsub_rn(xmax, xmin), (float)N_BINS);
    const float inv_delta = (delta > 0.0f) ? (1.0f / delta) : 0.0f;  // guess only
    const float4* __restrict__ xcr4 = (const float4*)xc;
    const int4* __restrict__ tgt4 = (const int4*)tgt;
    for (int iv = gid; iv < nv; iv += stride) {
      float xs[4];
      if (COMPACT) {
        float4 v = xcr4[iv];
        xs[0] = v.x; xs[1] = v.y; xs[2] = v.z; xs[3] = v.w;
      } else {
        xs[0] = in4[4 * iv + 0].x; xs[1] = in4[4 * iv + 1].x;
        xs[2] = in4[4 * iv + 2].x; xs[3] = in4[4 * iv + 3].x;
      }
      int4 tv = tgt4[iv];
      int ts[4] = {tv.x, tv.y, tv.z, tv.w};
#pragma unroll
      for (int k = 0; k < 4; ++k) {
        float x = xs[k];
        int cls = (ts[k] == 1) ? 0 : 1;
        int g = (int)((x - xmin) * inv_delta);
        g = max(0, min(g, EDGE_N));
        while (g < EDGE_N && s_edges[g] < x) ++g;   // exact: u = #edges < x
        while (g > 0 && s_edges[g - 1] >= x) --g;
        atomicAdd(&shU[cls * HIST_N + g], 1);
        if (g < EDGE_N && s_edges[g] == x) atomicAdd(&shE[cls * EDGE_N + g], 1);
      }
    }
    if (bid == 0 && tid < (n - base)) {
      int i = base + tid;
      float x = COMPACT ? xc[i] : in4[i].x;
      int cls = (tgt[i] == 1) ? 0 : 1;
      int g = (int)((x - xmin) * inv_delta);
      g = max(0, min(g, EDGE_N));
      while (g < EDGE_N && s_edges[g] < x) ++g;
      while (g > 0 && s_edges[g - 1] >= x) --g;
      atomicAdd(&shU[cls * HIST_N + g], 1);
      if (g < EDGE_N && s_edges[g] == x) atomicAdd(&shE[cls * EDGE_N + g], 1);
    }
  }
  __syncthreads();
  for (int k = tid; k < 2 * HIST_N; k += NTHR) {
    int val = shU[k];
    if (val) atomicAdd(&histU[k], val);
  }
  for (int k = tid; k < 2 * EDGE_N; k += NTHR) {
    int val = shE[k];
    if (val) atomicAdd(&histE[k], val);
  }
  grid.sync();

  // ---------------- Phase C: decide (every block, redundantly) ----------------
  for (int i = tid; i < 2 * HIST_N; i += NTHR) shU[i] = atom_ldi(&histU[i]);
  for (int i = tid; i < 2 * EDGE_N; i += NTHR) shE[i] = atom_ldi(&histE[i]);
  __syncthreads();
  if (tid == 0) {
    int aS = 0, aB = 0;
    for (int e = 0; e < EDGE_N; ++e) {
      aS += shU[e];
      aB += shU[HIST_N + e];
      s_ns_le[e] = aS;
      s_nb_le[e] = aB;
      s_ns_lt[e] = aS - shE[e];
      s_nb_lt[e] = aB - shE[EDGE_N + e];
    }
    int h0[N_BINS], h1[N_BINS];
    bool g0[N_BINS], g1[N_BINS];
    for (int k = 0; k < N_BINS; ++k) {
      h0[k] = s_nb_le[k + 1] - s_nb_lt[k];
      h1[k] = s_ns_le[k + 1] - s_ns_lt[k];
      g0[k] = h0[k] > h1[k];
      g1[k] = h1[k] > h0[k];
    }
    for (int e = 0; e < EDGE_N; ++e) s_mask[e] = 0;
    int cnt = 0;
    for (int k = 0; k + 1 < N_BINS; ++k) {
      bool c0 = (g0[k] != g0[k + 1]) && (h0[k] > 0);
      bool c1 = (g1[k] != g1[k + 1]) && (h1[k] > 0);
      if (c0 || c1) { s_mask[k + 1] = 1; ++cnt; }
    }
    if (cnt == 1) s_mask[N_BINS] = 1;
  }
  __syncthreads();
  {
    const int Ns = s_ns_le[EDGE_N - 1];
    const int Nb = n - Ns;
    float aC, bC;
    get_ab(aC, bC);
    const float n_f = (float)n;
    float best = INFINITY;
    int bestIdx = 0x7fffffff;
    for (int p = tid; p < EDGE_N * EDGE_N; p += NTHR) {
      int i = p / EDGE_N, j = p - i * EDGE_N;
      float v = INFINITY;
      if (s_mask[i] && s_mask[j] && i < j) {
        int c0 = s_ns_le[i] + (Nb - s_nb_le[i]);
        int c1 = Ns - s_ns_lt[i] + s_nb_lt[i];
        int c2 = s_ns_le[j] - s_ns_lt[i] + Nb - (s_nb_le[j] - s_nb_lt[i]);
        int c3 = s_ns_le[i] + Ns - s_ns_lt[j] + s_nb_le[j] - s_nb_lt[i];
        float L0 = bce_f(c0, n_f, aC, bC);
        float L1 = bce_f(c1, n_f, aC, bC);
        float L2 = bce_f(c2, n_f, aC, bC);
        float L3 = bce_f(c3, n_f, aC, bC);
        v = L0;
        if (L1 < v) v = L1;
        if (L2 < v) v = L2;
        if (L3 < v) v = L3;
      }
      if (v < best || (v == best && p < bestIdx)) { best = v; bestIdx = p; }
    }
    s_rv[tid] = best;
    s_ri[tid] = bestIdx;
    __syncthreads();
    for (int s = NTHR / 2; s > 0; s >>= 1) {
      if (tid < s) {
        float ov = s_rv[tid + s];
        int oi = s_ri[tid + s];
        if (ov < s_rv[tid] || (ov == s_rv[tid] && oi < s_ri[tid])) {
          s_rv[tid] = ov;
          s_ri[tid] = oi;
        }
      }
      __syncthreads();
    }
    if (tid == 0) {
      int p = s_ri[0];
      int i = p / EDGE_N, j = p - i * EDGE_N;
      int c0 = s_ns_le[i] + (Nb - s_nb_le[i]);
      int c1 = Ns - s_ns_lt[i] + s_nb_lt[i];
      int c2 = s_ns_le[j] - s_ns_lt[i] + Nb - (s_nb_le[j] - s_nb_lt[i]);
      int c3 = s_ns_le[i] + Ns - s_ns_lt[j] + s_nb_le[j] - s_nb_lt[i];
      float L0 = bce_f(c0, n_f, aC, bC);
      float L1 = bce_f(c1, n_f, aC, bC);
      float L2 = bce_f(c2, n_f, aC, bC);
      float L3 = bce_f(c3, n_f, aC, bC);
      int cs = 0;
      float m = L0;
      if (L1 < m) { m = L1; cs = 1; }
      if (L2 < m) { m = L2; cs = 2; }
      if (L3 < m) { m = L3; cs = 3; }
      s_cut[0] = s_edges[i];
      s_cut[1] = s_edges[j];
      s_case = cs;
    }
    __syncthreads();
  }

  // ---------------- Phase D: predict ----------------
  {
    const float lower = s_cut[0];
    const float upper = s_cut[1];
    const int cs = s_case;
    const float4* __restrict__ xcr4 = (const float4*)xc;
    int4* __restrict__ out4 = (int4*)out;
    for (int iv = gid; iv < nv; iv += stride) {
      float xs[4];
      if (COMPACT) {
        float4 v = xcr4[iv];
        xs[0] = v.x; xs[1] = v.y; xs[2] = v.z; xs[3] = v.w;
      } else {
        xs[0] = in4[4 * iv + 0].x; xs[1] = in4[4 * iv + 1].x;
        xs[2] = in4[4 * iv + 2].x; xs[3] = in4[4 * iv + 3].x;
      }
      int r[4];
#pragma unroll
      for (int k = 0; k < 4; ++k) {
        float x = xs[k];
        bool p;
        if (cs == 0) p = (x <= lower);
        else if (cs == 1) p = (x >= lower);
        else if (cs == 2) p = (x >= lower) && (x <= upper);
        else p = (x <= lower) || (x >= upper);
        r[k] = p ? 1 : 0;
      }
      out4[iv] = make_int4(r[0], r[1], r[2], r[3]);
    }
    if (bid == 0 && tid < (n - base)) {
      int i = base + tid;
      float x = COMPACT ? xc[i] : in4[i].x;
      bool p;
      if (cs == 0) p = (x <= lower);
      else if (cs == 1) p = (x >= lower);
      else if (cs == 2) p = (x >= lower) && (x <= upper);
      else p = (x <= lower) || (x >= upper);
      out[i] = p ? 1 : 0;
    }
  }
}

extern "C" void kernel_launch(void* const* d_in, const int* in_sizes, int n_in,
                              void* d_out, int out_size, void* d_ws, size_t ws_size,
                              hipStream_t stream) {
  const float4* in4 = (const float4*)d_in[0];
  const int* tgt = (const int*)d_in[1];
  int n = in_sizes[1];
  int* out = (int*)d_out;

  float* bmin = (float*)d_ws;
  float* bmax = bmin + NBLK;
  int* histU = (int*)(bmax + NBLK);
  int* histE = histU + 2 * HIST_N;
  float* xc = (float*)((char*)d_ws + 16384);
  const bool compact = ws_size >= (size_t)16384 + (size_t)n * 4u;

  void* args[9] = {(void*)&in4, (void*)&tgt, (void*)&n, (void*)&xc,
                   (void*)&bmin, (void*)&bmax, (void*)&histU, (void*)&histE,
                   (void*)&out};
  if (compact) {
    hipLaunchCooperativeKernel((void*)k_fused<1>, dim3(NBLK), dim3(NTHR), args, 0, stream);
  } else {
    hipLaunchCooperativeKernel((void*)k_fused<0>, dim3(NBLK), dim3(NTHR), args, 0, stream);
  }
}

// Round 4
// 113.424 us; speedup vs baseline: 2.7948x; 2.7948x over previous
//
#include <hip/hip_runtime.h>
#include <math.h>
#include <stdint.h>

#define N_BINS 50
#define EDGE_N 51
#define HIST_N 52
#define NBLK 2048
#define NTHR 256

typedef unsigned int u32;
typedef unsigned short u16;
typedef unsigned char u8;

// ws layout (bytes):
// [0]      float bmin[2048]          (per-block minima, plain stores each call)
// [8192]   float bmax[2048]
// [16384]  int cut[5]: {case, i, j, lower_f32_bits, upper_f32_bits}
// [16448]  int histU[2*52]           (U_sig, U_bkg; zeroed by k_minmax blk0)
// [+416]   int histE[2*51]           (equality counts per edge per class)
// [32768]  u8 codes[n]               (u | eq<<6 per element)
// [align16] float xc[n]              (compacted column 0)

// jnp.linspace(xmin, xmax, 51) float32 semantics:
//   step = e/50 (f32 div); out = xmin*(1-step) + xmax*step; endpoint = xmax exactly.
__device__ __forceinline__ float edge_at(int e, float xmin, float xmax) {
  if (e >= N_BINS) return xmax;
  float step = __fdiv_rn((float)e, (float)N_BINS);
  float omst = __fsub_rn(1.0f, step);
  return __fadd_rn(__fmul_rn(xmin, omst), __fmul_rn(xmax, step));
}

// bce(c) = ((n_f - c)*b + c*a)/n_f in exact f32 op order (no fma contraction)
__device__ __forceinline__ float bce_f(int c, float n_f, float aC, float bC) {
  float cf = (float)c;  // exact, c < 2^24
  float t = __fadd_rn(__fmul_rn(__fsub_rn(n_f, cf), bC), __fmul_rn(cf, aC));
  return __fdiv_rn(t, n_f);
}

__device__ __forceinline__ void get_ab(float& aC, float& bC) {
  const double epsd = (double)1e-7f;
  aC = (float)(-log1p(-epsd));
  bC = (float)(-log(epsd));
}

template <int COMPACT>
__global__ void k_minmax(const float4* __restrict__ in4, int n,
                         float* __restrict__ bmin, float* __restrict__ bmax,
                         int* __restrict__ histU, int* __restrict__ histE,
                         float* __restrict__ xc) {
  const int tid = threadIdx.x, bid = blockIdx.x;
  const int gid = bid * NTHR + tid;
  const int stride = NBLK * NTHR;
  const int nv = n >> 2;
  const int base = nv << 2;
  float4* __restrict__ xc4 = (float4*)xc;
  if (bid == 0) {  // zero global hists (stream-ordered before k_hist)
    for (int i = tid; i < 2 * HIST_N; i += NTHR) histU[i] = 0;
    for (int i = tid; i < 2 * EDGE_N; i += NTHR) histE[i] = 0;
  }
  float vmin = INFINITY, vmax = -INFINITY;
  for (int iv = gid; iv < nv; iv += stride) {
    float4 a = in4[4 * iv + 0];
    float4 b = in4[4 * iv + 1];
    float4 c = in4[4 * iv + 2];
    float4 d = in4[4 * iv + 3];
    vmin = fminf(fminf(vmin, fminf(a.x, b.x)), fminf(c.x, d.x));
    vmax = fmaxf(fmaxf(vmax, fmaxf(a.x, b.x)), fmaxf(c.x, d.x));
    if (COMPACT) xc4[iv] = make_float4(a.x, b.x, c.x, d.x);
  }
  if (bid == 0 && tid < (n - base)) {
    float x = in4[base + tid].x;
    vmin = fminf(vmin, x);
    vmax = fmaxf(vmax, x);
    if (COMPACT) xc[base + tid] = x;
  }
  for (int off = 32; off; off >>= 1) {
    vmin = fminf(vmin, __shfl_down(vmin, off));
    vmax = fmaxf(vmax, __shfl_down(vmax, off));
  }
  __shared__ float s_red[8];
  int wid = tid >> 6;
  if ((tid & 63) == 0) { s_red[wid] = vmin; s_red[4 + wid] = vmax; }
  __syncthreads();
  if (tid == 0) {
    float m = s_red[0], M = s_red[4];
    for (int w = 1; w < NTHR / 64; ++w) { m = fminf(m, s_red[w]); M = fmaxf(M, s_red[4 + w]); }
    bmin[bid] = m;
    bmax[bid] = M;
  }
}

template <int COMPACT>
__global__ void k_hist(const float4* __restrict__ in4, const float* __restrict__ xc,
                       const int* __restrict__ tgt, int n,
                       const float* __restrict__ bmin, const float* __restrict__ bmax,
                       int* __restrict__ histU, int* __restrict__ histE,
                       u8* __restrict__ codes) {
  // per-thread private counters: bank = (tid/2)%32 independent of bin -> conflict-free
  __shared__ u16 ph[HIST_N][NTHR];
  __shared__ float s_edges[EDGE_N];
  __shared__ int shE[2 * EDGE_N];
  __shared__ float s_red[8];
  __shared__ float s_mm[2];
  const int tid = threadIdx.x, bid = blockIdx.x;
  // global min/max from per-block results (L2-hot)
  {
    float m = INFINITY, M = -INFINITY;
    for (int i = tid; i < NBLK; i += NTHR) { m = fminf(m, bmin[i]); M = fmaxf(M, bmax[i]); }
    for (int off = 32; off; off >>= 1) {
      m = fminf(m, __shfl_down(m, off));
      M = fmaxf(M, __shfl_down(M, off));
    }
    int wid = tid >> 6;
    if ((tid & 63) == 0) { s_red[wid] = m; s_red[4 + wid] = M; }
    __syncthreads();
    if (tid == 0) {
      float mm = s_red[0], MM = s_red[4];
      for (int w = 1; w < NTHR / 64; ++w) { mm = fminf(mm, s_red[w]); MM = fmaxf(MM, s_red[4 + w]); }
      s_mm[0] = mm;
      s_mm[1] = MM;
    }
  }
  u32* ph32w = (u32*)&ph[0][0];
  for (int i = tid; i < HIST_N * (NTHR / 2); i += NTHR) ph32w[i] = 0;
  for (int i = tid; i < 2 * EDGE_N; i += NTHR) shE[i] = 0;
  __syncthreads();
  const float xmin = s_mm[0], xmax = s_mm[1];
  if (tid < EDGE_N) s_edges[tid] = edge_at(tid, xmin, xmax);
  __syncthreads();
  const float delta = __fdiv_rn(__fsub_rn(xmax, xmin), (float)N_BINS);
  const float inv_delta = (delta > 0.0f) ? (1.0f / delta) : 0.0f;  // guess only
  const int gid = bid * NTHR + tid;
  const int stride = NBLK * NTHR;
  const int nv = n >> 2;
  const int base = nv << 2;
  const float4* __restrict__ xc4 = (const float4*)xc;
  const int4* __restrict__ tgt4 = (const int4*)tgt;
  uchar4* __restrict__ codes4 = (uchar4*)codes;
  for (int iv = gid; iv < nv; iv += stride) {
    float xs[4];
    if (COMPACT) {
      float4 v = xc4[iv];
      xs[0] = v.x; xs[1] = v.y; xs[2] = v.z; xs[3] = v.w;
    } else {
      xs[0] = in4[4 * iv + 0].x; xs[1] = in4[4 * iv + 1].x;
      xs[2] = in4[4 * iv + 2].x; xs[3] = in4[4 * iv + 3].x;
    }
    int4 tv = tgt4[iv];
    int ts[4] = {tv.x, tv.y, tv.z, tv.w};
    u8 cd[4];
#pragma unroll
    for (int k = 0; k < 4; ++k) {
      float x = xs[k];
      int cls = (ts[k] == 1) ? 0 : 1;
      int g = (int)((x - xmin) * inv_delta);
      g = max(0, min(g, EDGE_N));
      while (g < EDGE_N && s_edges[g] < x) ++g;   // exact: u = #edges < x
      while (g > 0 && s_edges[g - 1] >= x) --g;
      int eq = (g < EDGE_N && s_edges[g] == x) ? 1 : 0;
      ph[g][tid] = (u16)(ph[g][tid] + (1u << (cls * 8)));
      if (eq) atomicAdd(&shE[cls * EDGE_N + g], 1);
      cd[k] = (u8)(g | (eq << 6));
    }
    if (COMPACT) codes4[iv] = make_uchar4(cd[0], cd[1], cd[2], cd[3]);
  }
  if (bid == 0 && tid < (n - base)) {
    int i = base + tid;
    float x = COMPACT ? xc[i] : in4[i].x;
    int cls = (tgt[i] == 1) ? 0 : 1;
    int g = (int)((x - xmin) * inv_delta);
    g = max(0, min(g, EDGE_N));
    while (g < EDGE_N && s_edges[g] < x) ++g;
    while (g > 0 && s_edges[g - 1] >= x) --g;
    int eq = (g < EDGE_N && s_edges[g] == x) ? 1 : 0;
    ph[g][tid] = (u16)(ph[g][tid] + (1u << (cls * 8)));
    if (eq) atomicAdd(&shE[cls * EDGE_N + g], 1);
    if (COMPACT) codes[i] = (u8)(g | (eq << 6));
  }
  __syncthreads();
  if (tid < HIST_N) {  // lanes 0..51 of wave 0; diagonal stagger -> <=2 lanes/bank
    const u32* ph32r = (const u32*)&ph[0][0];
    u32 c0 = 0, c1 = 0;
    for (int k2 = 0; k2 < NTHR / 2; ++k2) {
      int idx = (k2 + tid) & (NTHR / 2 - 1);
      u32 w = ph32r[tid * (NTHR / 2) + idx];
      c0 += (w & 0xFFu) + ((w >> 16) & 0xFFu);
      c1 += ((w >> 8) & 0xFFu) + ((w >> 24) & 0xFFu);
    }
    if (c0) atomicAdd(&histU[tid], (int)c0);
    if (c1) atomicAdd(&histU[HIST_N + tid], (int)c1);
  }
  for (int kk = tid; kk < 2 * EDGE_N; kk += NTHR) {
    int v = shE[kk];
    if (v) atomicAdd(&histE[kk], v);
  }
}

__global__ void k_decide(const float* __restrict__ bmin, const float* __restrict__ bmax,
                         const int* __restrict__ histU, const int* __restrict__ histE,
                         int n, int* __restrict__ cut) {
  __shared__ int s_ns_le[EDGE_N], s_ns_lt[EDGE_N], s_nb_le[EDGE_N], s_nb_lt[EDGE_N];
  __shared__ unsigned char s_mask[EDGE_N];
  __shared__ float s_edges[EDGE_N];
  __shared__ float s_rv[NTHR];
  __shared__ int s_ri[NTHR];
  __shared__ float s_red[8];
  __shared__ float s_mm[2];
  const int tid = threadIdx.x;
  {
    float m = INFINITY, M = -INFINITY;
    for (int i = tid; i < NBLK; i += NTHR) { m = fminf(m, bmin[i]); M = fmaxf(M, bmax[i]); }
    for (int off = 32; off; off >>= 1) {
      m = fminf(m, __shfl_down(m, off));
      M = fmaxf(M, __shfl_down(M, off));
    }
    int wid = tid >> 6;
    if ((tid & 63) == 0) { s_red[wid] = m; s_red[4 + wid] = M; }
    __syncthreads();
    if (tid == 0) {
      float mm = s_red[0], MM = s_red[4];
      for (int w = 1; w < NTHR / 64; ++w) { mm = fminf(mm, s_red[w]); MM = fmaxf(MM, s_red[4 + w]); }
      s_mm[0] = mm;
      s_mm[1] = MM;
    }
    __syncthreads();
  }
  if (tid < EDGE_N) s_edges[tid] = edge_at(tid, s_mm[0], s_mm[1]);
  if (tid == 0) {
    int aS = 0, aB = 0;
    for (int e = 0; e < EDGE_N; ++e) {
      aS += histU[e];
      aB += histU[HIST_N + e];
      s_ns_le[e] = aS;
      s_nb_le[e] = aB;
      s_ns_lt[e] = aS - histE[e];
      s_nb_lt[e] = aB - histE[EDGE_N + e];
    }
    int h0[N_BINS], h1[N_BINS];
    bool g0[N_BINS], g1[N_BINS];
    for (int k = 0; k < N_BINS; ++k) {
      h0[k] = s_nb_le[k + 1] - s_nb_lt[k];
      h1[k] = s_ns_le[k + 1] - s_ns_lt[k];
      g0[k] = h0[k] > h1[k];
      g1[k] = h1[k] > h0[k];
    }
    for (int e = 0; e < EDGE_N; ++e) s_mask[e] = 0;
    int cnt = 0;
    for (int k = 0; k + 1 < N_BINS; ++k) {
      bool c0 = (g0[k] != g0[k + 1]) && (h0[k] > 0);
      bool c1 = (g1[k] != g1[k + 1]) && (h1[k] > 0);
      if (c0 || c1) { s_mask[k + 1] = 1; ++cnt; }
    }
    if (cnt == 1) s_mask[N_BINS] = 1;
  }
  __syncthreads();
  const int Ns = s_ns_le[EDGE_N - 1];
  const int Nb = n - Ns;
  float aC, bC;
  get_ab(aC, bC);
  const float n_f = (float)n;
  float best = INFINITY;
  int bestIdx = 0x7fffffff;
  for (int p = tid; p < EDGE_N * EDGE_N; p += NTHR) {
    int i = p / EDGE_N, j = p - i * EDGE_N;
    float v = INFINITY;
    if (s_mask[i] && s_mask[j] && i < j) {
      int c0 = s_ns_le[i] + (Nb - s_nb_le[i]);
      int c1 = Ns - s_ns_lt[i] + s_nb_lt[i];
      int c2 = s_ns_le[j] - s_ns_lt[i] + Nb - (s_nb_le[j] - s_nb_lt[i]);
      int c3 = s_ns_le[i] + Ns - s_ns_lt[j] + s_nb_le[j] - s_nb_lt[i];
      float L0 = bce_f(c0, n_f, aC, bC);
      float L1 = bce_f(c1, n_f, aC, bC);
      float L2 = bce_f(c2, n_f, aC, bC);
      float L3 = bce_f(c3, n_f, aC, bC);
      v = L0;
      if (L1 < v) v = L1;
      if (L2 < v) v = L2;
      if (L3 < v) v = L3;
    }
    if (v < best || (v == best && p < bestIdx)) { best = v; bestIdx = p; }
  }
  s_rv[tid] = best;
  s_ri[tid] = bestIdx;
  __syncthreads();
  for (int s = NTHR / 2; s > 0; s >>= 1) {
    if (tid < s) {
      float ov = s_rv[tid + s];
      int oi = s_ri[tid + s];
      if (ov < s_rv[tid] || (ov == s_rv[tid] && oi < s_ri[tid])) {
        s_rv[tid] = ov;
        s_ri[tid] = oi;
      }
    }
    __syncthreads();
  }
  if (tid == 0) {
    int p = s_ri[0];
    int i = p / EDGE_N, j = p - i * EDGE_N;
    int c0 = s_ns_le[i] + (Nb - s_nb_le[i]);
    int c1 = Ns - s_ns_lt[i] + s_nb_lt[i];
    int c2 = s_ns_le[j] - s_ns_lt[i] + Nb - (s_nb_le[j] - s_nb_lt[i]);
    int c3 = s_ns_le[i] + Ns - s_ns_lt[j] + s_nb_le[j] - s_nb_lt[i];
    float L0 = bce_f(c0, n_f, aC, bC);
    float L1 = bce_f(c1, n_f, aC, bC);
    float L2 = bce_f(c2, n_f, aC, bC);
    float L3 = bce_f(c3, n_f, aC, bC);
    int cs = 0;
    float m = L0;
    if (L1 < m) { m = L1; cs = 1; }
    if (L2 < m) { m = L2; cs = 2; }
    if (L3 < m) { m = L3; cs = 3; }
    cut[0] = cs;
    cut[1] = i;
    cut[2] = j;
    ((float*)cut)[3] = s_edges[i];
    ((float*)cut)[4] = s_edges[j];
  }
}

__global__ void k_pred_codes(const u8* __restrict__ codes, int n,
                             const int* __restrict__ cut, int* __restrict__ out) {
  const int cs = cut[0], ci = cut[1], cj = cut[2];
  const int4* __restrict__ c16 = (const int4*)codes;
  int4* __restrict__ out4 = (int4*)out;
  const int ncv = n >> 4;
  const int gid = blockIdx.x * NTHR + threadIdx.x;
  const int stride = NBLK * NTHR;
  for (int iv = gid; iv < ncv; iv += stride) {
    int4 c = c16[iv];
    u32 wv[4] = {(u32)c.x, (u32)c.y, (u32)c.z, (u32)c.w};
#pragma unroll
    for (int q = 0; q < 4; ++q) {
      u32 w = wv[q];
      int r[4];
#pragma unroll
      for (int b = 0; b < 4; ++b) {
        u32 by = (w >> (8 * b)) & 0xFFu;
        int u = (int)(by & 63u);
        int v = u + (int)(by >> 6);
        bool p0 = (u <= ci), p1 = (ci < v);
        bool p = (cs == 0) ? p0 : (cs == 1) ? p1 : (cs == 2) ? (p1 && (u <= cj)) : (p0 || (cj < v));
        r[b] = p ? 1 : 0;
      }
      out4[iv * 4 + q] = make_int4(r[0], r[1], r[2], r[3]);
    }
  }
  const int base = ncv << 4;
  if (blockIdx.x == 0 && threadIdx.x < (n - base)) {
    int i = base + threadIdx.x;
    u32 by = codes[i];
    int u = (int)(by & 63u);
    int v = u + (int)(by >> 6);
    bool p0 = (u <= ci), p1 = (ci < v);
    bool p = (cs == 0) ? p0 : (cs == 1) ? p1 : (cs == 2) ? (p1 && (u <= cj)) : (p0 || (cj < v));
    out[i] = p ? 1 : 0;
  }
}

__global__ void k_pred_f(const float4* __restrict__ in4, int n,
                         const int* __restrict__ cut, int* __restrict__ out) {
  const int cs = cut[0];
  const float lower = ((const float*)cut)[3];
  const float upper = ((const float*)cut)[4];
  int4* __restrict__ out4 = (int4*)out;
  const int nv = n >> 2;
  const int gid = blockIdx.x * NTHR + threadIdx.x;
  const int stride = NBLK * NTHR;
  for (int iv = gid; iv < nv; iv += stride) {
    float xs[4] = {in4[4 * iv + 0].x, in4[4 * iv + 1].x, in4[4 * iv + 2].x, in4[4 * iv + 3].x};
    int r[4];
#pragma unroll
    for (int k = 0; k < 4; ++k) {
      float x = xs[k];
      bool p;
      if (cs == 0) p = (x <= lower);
      else if (cs == 1) p = (x >= lower);
      else if (cs == 2) p = (x >= lower) && (x <= upper);
      else p = (x <= lower) || (x >= upper);
      r[k] = p ? 1 : 0;
    }
    out4[iv] = make_int4(r[0], r[1], r[2], r[3]);
  }
  const int base = nv << 2;
  if (blockIdx.x == 0 && threadIdx.x < (n - base)) {
    int i = base + threadIdx.x;
    float x = in4[i].x;
    bool p;
    if (cs == 0) p = (x <= lower);
    else if (cs == 1) p = (x >= lower);
    else if (cs == 2) p = (x >= lower) && (x <= upper);
    else p = (x <= lower) || (x >= upper);
    out[i] = p ? 1 : 0;
  }
}

extern "C" void kernel_launch(void* const* d_in, const int* in_sizes, int n_in,
                              void* d_out, int out_size, void* d_ws, size_t ws_size,
                              hipStream_t stream) {
  const float4* in4 = (const float4*)d_in[0];
  const int* tgt = (const int*)d_in[1];
  int n = in_sizes[1];
  int* out = (int*)d_out;
  char* ws = (char*)d_ws;
  float* bmin = (float*)ws;
  float* bmax = (float*)(ws + 8192);
  int* cut = (int*)(ws + 16384);
  int* histU = (int*)(ws + 16448);
  int* histE = histU + 2 * HIST_N;
  u8* codes = (u8*)(ws + 32768);
  size_t xcOff = ((size_t)32768 + (size_t)n + 15) & ~(size_t)15;
  float* xc = (float*)(ws + xcOff);
  const bool compact = ws_size >= xcOff + (size_t)n * 4u;

  if (compact) {
    k_minmax<1><<<NBLK, NTHR, 0, stream>>>(in4, n, bmin, bmax, histU, histE, xc);
    k_hist<1><<<NBLK, NTHR, 0, stream>>>(in4, xc, tgt, n, bmin, bmax, histU, histE, codes);
    k_decide<<<1, NTHR, 0, stream>>>(bmin, bmax, histU, histE, n, cut);
    k_pred_codes<<<NBLK, NTHR, 0, stream>>>(codes, n, cut, out);
  } else {
    k_minmax<0><<<NBLK, NTHR, 0, stream>>>(in4, n, bmin, bmax, histU, histE, nullptr);
    k_hist<0><<<NBLK, NTHR, 0, stream>>>(in4, nullptr, tgt, n, bmin, bmax, histU, histE, nullptr);
    k_decide<<<1, NTHR, 0, stream>>>(bmin, bmax, histU, histE, n, cut);
    k_pred_f<<<NBLK, NTHR, 0, stream>>>(in4, n, cut, out);
  }
}

// Round 5
// 105.288 us; speedup vs baseline: 3.0108x; 1.0773x over previous
//
#include <hip/hip_runtime.h>
#include <math.h>
#include <stdint.h>

#define N_BINS 50
#define EDGE_N 51
#define HIST_N 52
#define NBLK 2048
#define NTHR 256

typedef unsigned int u32;
typedef unsigned short u16;
typedef unsigned char u8;

// ws layout (bytes):
// [0]      float bmin[2048]          (per-block minima, plain stores each call)
// [8192]   float bmax[2048]
// [16448]  int histU[2*52]           (U_sig, U_bkg; zeroed by k_minmax blk0)
// [+416]   int histE[2*51]           (equality counts per edge per class)
// [32768]  u8 codes[n]               (u | eq<<6 per element)
// [align16] float xc[n]              (compacted column 0)

// jnp.linspace(xmin, xmax, 51) float32 semantics:
//   step = e/50 (f32 div); out = xmin*(1-step) + xmax*step; endpoint = xmax exactly.
__device__ __forceinline__ float edge_at(int e, float xmin, float xmax) {
  if (e >= N_BINS) return xmax;
  float step = __fdiv_rn((float)e, (float)N_BINS);
  float omst = __fsub_rn(1.0f, step);
  return __fadd_rn(__fmul_rn(xmin, omst), __fmul_rn(xmax, step));
}

// bce(c) = ((n_f - c)*b + c*a)/n_f in exact f32 op order (no fma contraction)
__device__ __forceinline__ float bce_f(int c, float n_f, float aC, float bC) {
  float cf = (float)c;  // exact, c < 2^24
  float t = __fadd_rn(__fmul_rn(__fsub_rn(n_f, cf), bC), __fmul_rn(cf, aC));
  return __fdiv_rn(t, n_f);
}

__device__ __forceinline__ void get_ab(float& aC, float& bC) {
  const double epsd = (double)1e-7f;
  aC = (float)(-log1p(-epsd));
  bC = (float)(-log(epsd));
}

// block-wide min/max of bmin/bmax[NBLK] -> s_mm[2] (every block, identical result)
__device__ __forceinline__ void global_minmax(const float* __restrict__ bmin,
                                              const float* __restrict__ bmax,
                                              float* s_red, float* s_mm) {
  const int tid = threadIdx.x;
  float m = INFINITY, M = -INFINITY;
  for (int i = tid; i < NBLK; i += NTHR) { m = fminf(m, bmin[i]); M = fmaxf(M, bmax[i]); }
  for (int off = 32; off; off >>= 1) {
    m = fminf(m, __shfl_down(m, off));
    M = fmaxf(M, __shfl_down(M, off));
  }
  int wid = tid >> 6;
  if ((tid & 63) == 0) { s_red[wid] = m; s_red[4 + wid] = M; }
  __syncthreads();
  if (tid == 0) {
    float mm = s_red[0], MM = s_red[4];
    for (int w = 1; w < NTHR / 64; ++w) { mm = fminf(mm, s_red[w]); MM = fmaxf(MM, s_red[4 + w]); }
    s_mm[0] = mm;
    s_mm[1] = MM;
  }
  __syncthreads();
}

template <int COMPACT>
__global__ void k_minmax(const float4* __restrict__ in4, int n,
                         float* __restrict__ bmin, float* __restrict__ bmax,
                         int* __restrict__ histU, int* __restrict__ histE,
                         float* __restrict__ xc) {
  const int tid = threadIdx.x, bid = blockIdx.x;
  const int gid = bid * NTHR + tid;
  const int stride = NBLK * NTHR;
  const int nv = n >> 2;
  const int base = nv << 2;
  float4* __restrict__ xc4 = (float4*)xc;
  if (bid == 0) {  // zero global hists (stream-ordered before k_hist)
    for (int i = tid; i < 2 * HIST_N; i += NTHR) histU[i] = 0;
    for (int i = tid; i < 2 * EDGE_N; i += NTHR) histE[i] = 0;
  }
  float vmin = INFINITY, vmax = -INFINITY;
  for (int iv = gid; iv < nv; iv += stride) {
    float4 a = in4[4 * iv + 0];
    float4 b = in4[4 * iv + 1];
    float4 c = in4[4 * iv + 2];
    float4 d = in4[4 * iv + 3];
    vmin = fminf(fminf(vmin, fminf(a.x, b.x)), fminf(c.x, d.x));
    vmax = fmaxf(fmaxf(vmax, fmaxf(a.x, b.x)), fmaxf(c.x, d.x));
    if (COMPACT) xc4[iv] = make_float4(a.x, b.x, c.x, d.x);
  }
  if (bid == 0 && tid < (n - base)) {
    float x = in4[base + tid].x;
    vmin = fminf(vmin, x);
    vmax = fmaxf(vmax, x);
    if (COMPACT) xc[base + tid] = x;
  }
  for (int off = 32; off; off >>= 1) {
    vmin = fminf(vmin, __shfl_down(vmin, off));
    vmax = fmaxf(vmax, __shfl_down(vmax, off));
  }
  __shared__ float s_red[8];
  int wid = tid >> 6;
  if ((tid & 63) == 0) { s_red[wid] = vmin; s_red[4 + wid] = vmax; }
  __syncthreads();
  if (tid == 0) {
    float m = s_red[0], M = s_red[4];
    for (int w = 1; w < NTHR / 64; ++w) { m = fminf(m, s_red[w]); M = fmaxf(M, s_red[4 + w]); }
    bmin[bid] = m;
    bmax[bid] = M;
  }
}

template <int COMPACT>
__global__ void k_hist(const float4* __restrict__ in4, const float* __restrict__ xc,
                       const int* __restrict__ tgt, int n,
                       const float* __restrict__ bmin, const float* __restrict__ bmax,
                       int* __restrict__ histU, int* __restrict__ histE,
                       u8* __restrict__ codes) {
  // per-thread private counters: bank = (tid/2)%32 independent of bin -> conflict-free
  __shared__ u16 ph[HIST_N][NTHR];
  __shared__ float s_edges[EDGE_N];
  __shared__ int shE[2 * EDGE_N];
  __shared__ float s_red[8];
  __shared__ float s_mm[2];
  const int tid = threadIdx.x, bid = blockIdx.x;
  global_minmax(bmin, bmax, s_red, s_mm);
  u32* ph32w = (u32*)&ph[0][0];
  for (int i = tid; i < HIST_N * (NTHR / 2); i += NTHR) ph32w[i] = 0;
  for (int i = tid; i < 2 * EDGE_N; i += NTHR) shE[i] = 0;
  const float xmin = s_mm[0], xmax = s_mm[1];
  if (tid < EDGE_N) s_edges[tid] = edge_at(tid, xmin, xmax);
  __syncthreads();
  const float delta = __fdiv_rn(__fsub_rn(xmax, xmin), (float)N_BINS);
  const float inv_delta = (delta > 0.0f) ? (1.0f / delta) : 0.0f;  // guess only
  const int gid = bid * NTHR + tid;
  const int stride = NBLK * NTHR;
  const int nv = n >> 2;
  const int base = nv << 2;
  const float4* __restrict__ xc4 = (const float4*)xc;
  const int4* __restrict__ tgt4 = (const int4*)tgt;
  uchar4* __restrict__ codes4 = (uchar4*)codes;
  for (int iv = gid; iv < nv; iv += stride) {
    float xs[4];
    if (COMPACT) {
      float4 v = xc4[iv];
      xs[0] = v.x; xs[1] = v.y; xs[2] = v.z; xs[3] = v.w;
    } else {
      xs[0] = in4[4 * iv + 0].x; xs[1] = in4[4 * iv + 1].x;
      xs[2] = in4[4 * iv + 2].x; xs[3] = in4[4 * iv + 3].x;
    }
    int4 tv = tgt4[iv];
    int ts[4] = {tv.x, tv.y, tv.z, tv.w};
    u8 cd[4];
#pragma unroll
    for (int k = 0; k < 4; ++k) {
      float x = xs[k];
      int cls = (ts[k] == 1) ? 0 : 1;
      int g = (int)((x - xmin) * inv_delta);
      g = max(0, min(g, EDGE_N));
      while (g < EDGE_N && s_edges[g] < x) ++g;   // exact: u = #edges < x
      while (g > 0 && s_edges[g - 1] >= x) --g;
      int eq = (g < EDGE_N && s_edges[g] == x) ? 1 : 0;
      ph[g][tid] = (u16)(ph[g][tid] + (1u << (cls * 8)));
      if (eq) atomicAdd(&shE[cls * EDGE_N + g], 1);
      cd[k] = (u8)(g | (eq << 6));
    }
    if (COMPACT) codes4[iv] = make_uchar4(cd[0], cd[1], cd[2], cd[3]);
  }
  if (bid == 0 && tid < (n - base)) {
    int i = base + tid;
    float x = COMPACT ? xc[i] : in4[i].x;
    int cls = (tgt[i] == 1) ? 0 : 1;
    int g = (int)((x - xmin) * inv_delta);
    g = max(0, min(g, EDGE_N));
    while (g < EDGE_N && s_edges[g] < x) ++g;
    while (g > 0 && s_edges[g - 1] >= x) --g;
    int eq = (g < EDGE_N && s_edges[g] == x) ? 1 : 0;
    ph[g][tid] = (u16)(ph[g][tid] + (1u << (cls * 8)));
    if (eq) atomicAdd(&shE[cls * EDGE_N + g], 1);
    if (COMPACT) codes[i] = (u8)(g | (eq << 6));
  }
  __syncthreads();
  if (tid < HIST_N) {  // lanes 0..51 of wave 0; diagonal stagger -> <=2 lanes/bank
    const u32* ph32r = (const u32*)&ph[0][0];
    u32 c0 = 0, c1 = 0;
    for (int k2 = 0; k2 < NTHR / 2; ++k2) {
      int idx = (k2 + tid) & (NTHR / 2 - 1);
      u32 w = ph32r[tid * (NTHR / 2) + idx];
      c0 += (w & 0xFFu) + ((w >> 16) & 0xFFu);
      c1 += ((w >> 8) & 0xFFu) + ((w >> 24) & 0xFFu);
    }
    if (c0) atomicAdd(&histU[tid], (int)c0);
    if (c1) atomicAdd(&histU[HIST_N + tid], (int)c1);
  }
  for (int kk = tid; kk < 2 * EDGE_N; kk += NTHR) {
    int v = shE[kk];
    if (v) atomicAdd(&histE[kk], v);
  }
}

// decide (redundant per block, bit-identical) + predict, fused
template <int COMPACT>
__global__ void k_decide_pred(const float4* __restrict__ in4, const u8* __restrict__ codes,
                              int n, const float* __restrict__ bmin,
                              const float* __restrict__ bmax,
                              const int* __restrict__ histU, const int* __restrict__ histE,
                              int* __restrict__ out) {
  __shared__ float s_red[8];
  __shared__ float s_mm[2];
  __shared__ int s_ns_le[EDGE_N], s_ns_lt[EDGE_N], s_nb_le[EDGE_N], s_nb_lt[EDGE_N];
  __shared__ int s_h0[N_BINS], s_h1[N_BINS];
  __shared__ unsigned char s_g0[N_BINS], s_g1[N_BINS];
  __shared__ unsigned char s_mask[EDGE_N];
  __shared__ float s_rv[NTHR];
  __shared__ int s_ri[NTHR];
  __shared__ int s_cut[3];  // case, i, j
  const int tid = threadIdx.x, bid = blockIdx.x;

  global_minmax(bmin, bmax, s_red, s_mm);

  // ---- wave-parallel prefix sums: wave0=sig, wave1=bkg ----
  if (tid < 128) {
    const int lane = tid & 63;
    const int w = tid >> 6;  // 0: sig, 1: bkg
    int v = (lane < EDGE_N) ? histU[w * HIST_N + lane] : 0;
#pragma unroll
    for (int d = 1; d < 64; d <<= 1) {
      int t = __shfl_up(v, d);
      if (lane >= d) v += t;
    }
    if (lane < EDGE_N) {
      int e = histE[w * EDGE_N + lane];
      if (w == 0) { s_ns_le[lane] = v; s_ns_lt[lane] = v - e; }
      else        { s_nb_le[lane] = v; s_nb_lt[lane] = v - e; }
    }
  }
  if (tid < EDGE_N) s_mask[tid] = 0;
  __syncthreads();
  if (tid < N_BINS) {
    int h0 = s_nb_le[tid + 1] - s_nb_lt[tid];
    int h1 = s_ns_le[tid + 1] - s_ns_lt[tid];
    s_h0[tid] = h0;
    s_h1[tid] = h1;
    s_g0[tid] = h0 > h1;
    s_g1[tid] = h1 > h0;
  }
  __syncthreads();
  if (tid < 64) {  // wave 0: cand for k=0..48 -> mask[k+1]; cnt via ballot
    bool cand = false;
    if (tid + 1 < N_BINS) {
      bool c0 = (s_g0[tid] != s_g0[tid + 1]) && (s_h0[tid] > 0);
      bool c1 = (s_g1[tid] != s_g1[tid + 1]) && (s_h1[tid] > 0);
      cand = c0 || c1;
      if (cand) s_mask[tid + 1] = 1;
    }
    unsigned long long bal = __ballot(cand);
    if (tid == 0 && __popcll(bal) == 1) s_mask[N_BINS] = 1;
  }
  __syncthreads();
  const int Ns = s_ns_le[EDGE_N - 1];
  const int Nb = n - Ns;
  float aC, bC;
  get_ab(aC, bC);
  const float n_f = (float)n;
  float best = INFINITY;
  int bestIdx = 0x7fffffff;
  for (int p = tid; p < EDGE_N * EDGE_N; p += NTHR) {
    int i = p / EDGE_N, j = p - i * EDGE_N;
    float v = INFINITY;
    if (s_mask[i] && s_mask[j] && i < j) {
      int c0 = s_ns_le[i] + (Nb - s_nb_le[i]);
      int c1 = Ns - s_ns_lt[i] + s_nb_lt[i];
      int c2 = s_ns_le[j] - s_ns_lt[i] + Nb - (s_nb_le[j] - s_nb_lt[i]);
      int c3 = s_ns_le[i] + Ns - s_ns_lt[j] + s_nb_le[j] - s_nb_lt[i];
      float L0 = bce_f(c0, n_f, aC, bC);
      float L1 = bce_f(c1, n_f, aC, bC);
      float L2 = bce_f(c2, n_f, aC, bC);
      float L3 = bce_f(c3, n_f, aC, bC);
      v = L0;
      if (L1 < v) v = L1;
      if (L2 < v) v = L2;
      if (L3 < v) v = L3;
    }
    if (v < best || (v == best && p < bestIdx)) { best = v; bestIdx = p; }
  }
  s_rv[tid] = best;
  s_ri[tid] = bestIdx;
  __syncthreads();
  for (int s = NTHR / 2; s > 0; s >>= 1) {
    if (tid < s) {
      float ov = s_rv[tid + s];
      int oi = s_ri[tid + s];
      if (ov < s_rv[tid] || (ov == s_rv[tid] && oi < s_ri[tid])) {
        s_rv[tid] = ov;
        s_ri[tid] = oi;
      }
    }
    __syncthreads();
  }
  if (tid == 0) {
    int p = s_ri[0];
    int i = p / EDGE_N, j = p - i * EDGE_N;
    int c0 = s_ns_le[i] + (Nb - s_nb_le[i]);
    int c1 = Ns - s_ns_lt[i] + s_nb_lt[i];
    int c2 = s_ns_le[j] - s_ns_lt[i] + Nb - (s_nb_le[j] - s_nb_lt[i]);
    int c3 = s_ns_le[i] + Ns - s_ns_lt[j] + s_nb_le[j] - s_nb_lt[i];
    float L0 = bce_f(c0, n_f, aC, bC);
    float L1 = bce_f(c1, n_f, aC, bC);
    float L2 = bce_f(c2, n_f, aC, bC);
    float L3 = bce_f(c3, n_f, aC, bC);
    int cs = 0;
    float m = L0;
    if (L1 < m) { m = L1; cs = 1; }
    if (L2 < m) { m = L2; cs = 2; }
    if (L3 < m) { m = L3; cs = 3; }
    s_cut[0] = cs;
    s_cut[1] = i;
    s_cut[2] = j;
  }
  __syncthreads();

  // ---- predict ----
  const int cs = s_cut[0], ci = s_cut[1], cj = s_cut[2];
  const int gid = bid * NTHR + tid;
  const int stride = NBLK * NTHR;
  if (COMPACT) {
    const int4* __restrict__ c16 = (const int4*)codes;
    int4* __restrict__ out4 = (int4*)out;
    const int ncv = n >> 4;
    for (int iv = gid; iv < ncv; iv += stride) {
      int4 c = c16[iv];
      u32 wv[4] = {(u32)c.x, (u32)c.y, (u32)c.z, (u32)c.w};
#pragma unroll
      for (int q = 0; q < 4; ++q) {
        u32 w = wv[q];
        int r[4];
#pragma unroll
        for (int b = 0; b < 4; ++b) {
          u32 by = (w >> (8 * b)) & 0xFFu;
          int u = (int)(by & 63u);
          int v = u + (int)(by >> 6);
          bool p0 = (u <= ci), p1 = (ci < v);
          bool p = (cs == 0) ? p0 : (cs == 1) ? p1 : (cs == 2) ? (p1 && (u <= cj)) : (p0 || (cj < v));
          r[b] = p ? 1 : 0;
        }
        out4[iv * 4 + q] = make_int4(r[0], r[1], r[2], r[3]);
      }
    }
    const int cbase = ncv << 4;
    if (bid == 0 && tid < (n - cbase)) {
      int i = cbase + tid;
      u32 by = codes[i];
      int u = (int)(by & 63u);
      int v = u + (int)(by >> 6);
      bool p0 = (u <= ci), p1 = (ci < v);
      bool p = (cs == 0) ? p0 : (cs == 1) ? p1 : (cs == 2) ? (p1 && (u <= cj)) : (p0 || (cj < v));
      out[i] = p ? 1 : 0;
    }
  } else {
    const float xmin = s_mm[0], xmax = s_mm[1];
    const float lower = edge_at(ci, xmin, xmax);
    const float upper = edge_at(cj, xmin, xmax);
    int4* __restrict__ out4 = (int4*)out;
    const int nv = n >> 2;
    for (int iv = gid; iv < nv; iv += stride) {
      float xs[4] = {in4[4 * iv + 0].x, in4[4 * iv + 1].x, in4[4 * iv + 2].x, in4[4 * iv + 3].x};
      int r[4];
#pragma unroll
      for (int k = 0; k < 4; ++k) {
        float x = xs[k];
        bool p;
        if (cs == 0) p = (x <= lower);
        else if (cs == 1) p = (x >= lower);
        else if (cs == 2) p = (x >= lower) && (x <= upper);
        else p = (x <= lower) || (x >= upper);
        r[k] = p ? 1 : 0;
      }
      out4[iv] = make_int4(r[0], r[1], r[2], r[3]);
    }
    const int fbase = nv << 2;
    if (bid == 0 && tid < (n - fbase)) {
      int i = fbase + tid;
      float x = in4[i].x;
      bool p;
      if (cs == 0) p = (x <= lower);
      else if (cs == 1) p = (x >= lower);
      else if (cs == 2) p = (x >= lower) && (x <= upper);
      else p = (x <= lower) || (x >= upper);
      out[i] = p ? 1 : 0;
    }
  }
}

extern "C" void kernel_launch(void* const* d_in, const int* in_sizes, int n_in,
                              void* d_out, int out_size, void* d_ws, size_t ws_size,
                              hipStream_t stream) {
  const float4* in4 = (const float4*)d_in[0];
  const int* tgt = (const int*)d_in[1];
  int n = in_sizes[1];
  int* out = (int*)d_out;
  char* ws = (char*)d_ws;
  float* bmin = (float*)ws;
  float* bmax = (float*)(ws + 8192);
  int* histU = (int*)(ws + 16448);
  int* histE = histU + 2 * HIST_N;
  u8* codes = (u8*)(ws + 32768);
  size_t xcOff = ((size_t)32768 + (size_t)n + 15) & ~(size_t)15;
  float* xc = (float*)(ws + xcOff);
  const bool compact = ws_size >= xcOff + (size_t)n * 4u;

  if (compact) {
    k_minmax<1><<<NBLK, NTHR, 0, stream>>>(in4, n, bmin, bmax, histU, histE, xc);
    k_hist<1><<<NBLK, NTHR, 0, stream>>>(in4, xc, tgt, n, bmin, bmax, histU, histE, codes);
    k_decide_pred<1><<<NBLK, NTHR, 0, stream>>>(in4, codes, n, bmin, bmax, histU, histE, out);
  } else {
    k_minmax<0><<<NBLK, NTHR, 0, stream>>>(in4, n, bmin, bmax, histU, histE, nullptr);
    k_hist<0><<<NBLK, NTHR, 0, stream>>>(in4, nullptr, tgt, n, bmin, bmax, histU, histE, nullptr);
    k_decide_pred<0><<<NBLK, NTHR, 0, stream>>>(in4, nullptr, n, bmin, bmax, histU, histE, out);
  }
}